// Round 8
// baseline (143.706 us; speedup 1.0000x reference)
//
#include <hip/hip_runtime.h>

// B=4, T=2048, D=1024, DK=128. Inputs fp32, output fp32.
// bf16 MFMA everywhere (16x16x32), fp32 accumulate.
// Layouts (HW-verified): A[m=lane&15][k=quad*8+j], B[n=lane&15][k=quad*8+j],
// C/D[col=lane&15][row=quad*4+reg].
// R16: R7 (cooperative staging) worked: 155.8->139.0, attn below the 42us
//      harness fill. attn is now LDS-BW/barrier bound (164KB LDS traffic,
//      4 barriers per 128-key iter). This round: wave w loads its OWN
//      16-key K strip direct from global (contiguous 4KB, L2-hot — NOT the
//      R4-6 whole-chunk-per-wave disease), V+P stay in LDS. 2 barriers,
//      100KB LDS traffic per iter; V prefetch hidden under PV; Wo epilogue
//      loads pipelined. qkv/prep unchanged to isolate the delta.
#define BATCH 4
#define T_SEQ 2048
#define D_MODEL 1024
#define DK 128
#define M_ROWS 8192
#define SCALE 0.088388347648318447f     // 1/sqrt(128)

typedef __attribute__((ext_vector_type(8))) short short8;
typedef __attribute__((ext_vector_type(4))) float f32x4;

__device__ __forceinline__ unsigned short f2b(float f) {
    unsigned int x = __float_as_uint(f);
    return (unsigned short)((x + 0x7FFFu + ((x >> 16) & 1u)) >> 16);  // RNE
}

// ---------------------------------------------------------------------------
// prep_w: weights fp32 -> bf16, transposed to k-contiguous. grid (16,4), 256.
//   p<3 : Wt[p][n=128][k=1024] = W_p[k][n]
//   p==3: Wot[n=1024][k=128]   = Wo[k][n]
// ---------------------------------------------------------------------------
__global__ __launch_bounds__(256) void prep_w(
    const float* __restrict__ Wq, const float* __restrict__ Wk,
    const float* __restrict__ Wv, const float* __restrict__ Wo,
    unsigned short* __restrict__ Wt, unsigned short* __restrict__ Wot)
{
    __shared__ unsigned short t[64][132];
    const int tid = threadIdx.x;
    const int p = blockIdx.y;
    if (p < 3) {
        const float* W = (p == 0) ? Wq : (p == 1) ? Wk : Wv;
        const int k0 = blockIdx.x * 64;
        #pragma unroll
        for (int i = 0; i < 8; i++) {
            int u = tid + 256 * i;              // 2048 float4 units (64k x 32)
            int r = u >> 5, c4 = u & 31;
            float4 v = *(const float4*)(W + (size_t)(k0 + r) * DK + c4 * 4);
            *(ushort4*)&t[r][c4 * 4] = make_ushort4(f2b(v.x), f2b(v.y), f2b(v.z), f2b(v.w));
        }
        __syncthreads();
        unsigned short* outp = Wt + (size_t)p * DK * D_MODEL;
        #pragma unroll
        for (int i = 0; i < 8; i++) {
            int u = tid + 256 * i;              // 128n x 16 k-quads
            int n = u >> 4, k4 = u & 15;
            ushort4 o = make_ushort4(t[k4 * 4 + 0][n], t[k4 * 4 + 1][n],
                                     t[k4 * 4 + 2][n], t[k4 * 4 + 3][n]);
            *(ushort4*)(outp + (size_t)n * D_MODEL + k0 + k4 * 4) = o;
        }
    } else {
        const int kt = blockIdx.x & 1, nt = blockIdx.x >> 1;
        const int k0 = kt * 64, n0 = nt * 128;
        #pragma unroll
        for (int i = 0; i < 8; i++) {
            int u = tid + 256 * i;
            int r = u >> 5, c4 = u & 31;
            float4 v = *(const float4*)(Wo + (size_t)(k0 + r) * D_MODEL + n0 + c4 * 4);
            *(ushort4*)&t[r][c4 * 4] = make_ushort4(f2b(v.x), f2b(v.y), f2b(v.z), f2b(v.w));
        }
        __syncthreads();
        #pragma unroll
        for (int i = 0; i < 8; i++) {
            int u = tid + 256 * i;
            int n = u >> 4, k4 = u & 15;
            ushort4 o = make_ushort4(t[k4 * 4 + 0][n], t[k4 * 4 + 1][n],
                                     t[k4 * 4 + 2][n], t[k4 * 4 + 3][n]);
            *(ushort4*)(Wot + (size_t)(n0 + n) * DK + k0 + k4 * 4) = o;
        }
    }
}

// ---------------------------------------------------------------------------
// qkv_mfma (fused Q,K,V): grid 512 (= 256 rowTiles x 2 colHalves), block 256
// (4 waves). Block: 32 rows x 64 cols of all 3 projections. (unchanged)
// ---------------------------------------------------------------------------
__global__ __launch_bounds__(256, 2) void qkv_mfma(
    const float* __restrict__ x, const unsigned short* __restrict__ Wt,
    unsigned short* __restrict__ Qb, unsigned short* __restrict__ Kb,
    unsigned short* __restrict__ Vt)
{
    const int row0 = (blockIdx.x >> 1) * 32;
    const int ch   = blockIdx.x & 1;         // col half: cols ch*64 .. +63
    const int tid = threadIdx.x;
    const int w = tid >> 6, lane = tid & 63;
    const int l15 = lane & 15, quad = lane >> 4;
    const int rg = w & 1, nh = w >> 1;

    __shared__ unsigned short xs[32][72];        // 4.6 KB
    __shared__ unsigned short Ws[3][64][72];     // 27.6 KB

    f32x4 acc[3][2];
    #pragma unroll
    for (int p = 0; p < 3; p++)
        #pragma unroll
        for (int n = 0; n < 2; n++) acc[p][n] = (f32x4)(0.f);

    float4 xv[2];
    short8 wv[6];
    #pragma unroll
    for (int i = 0; i < 2; i++) {               // preload x chunk 0 (32r x 64k fp32)
        int u = tid + 256 * i;
        int r = u >> 4, c4 = u & 15;
        xv[i] = *(const float4*)(x + (size_t)(row0 + r) * D_MODEL + c4 * 4);
    }
    #pragma unroll
    for (int i = 0; i < 6; i++) {               // preload W chunk 0 (3p x 64n x 64k)
        int u = tid + 256 * i;
        int p = u >> 9, rem = u & 511, n = rem >> 3, c8 = rem & 7;
        wv[i] = *(const short8*)(Wt + (size_t)p * DK * D_MODEL
                                  + (size_t)(ch * 64 + n) * D_MODEL + c8 * 8);
    }

    for (int k0 = 0; k0 < D_MODEL; k0 += 64) {
        #pragma unroll
        for (int i = 0; i < 2; i++) {
            int u = tid + 256 * i;
            int r = u >> 4, c4 = u & 15;
            *(ushort4*)&xs[r][c4 * 4] =
                make_ushort4(f2b(xv[i].x), f2b(xv[i].y), f2b(xv[i].z), f2b(xv[i].w));
        }
        #pragma unroll
        for (int i = 0; i < 6; i++) {
            int u = tid + 256 * i;
            int p = u >> 9, rem = u & 511, n = rem >> 3, c8 = rem & 7;
            *(short8*)&Ws[p][n][c8 * 8] = wv[i];
        }
        __syncthreads();
        if (k0 + 64 < D_MODEL) {                // issue next chunk loads under MFMA
            #pragma unroll
            for (int i = 0; i < 2; i++) {
                int u = tid + 256 * i;
                int r = u >> 4, c4 = u & 15;
                xv[i] = *(const float4*)(x + (size_t)(row0 + r) * D_MODEL + k0 + 64 + c4 * 4);
            }
            #pragma unroll
            for (int i = 0; i < 6; i++) {
                int u = tid + 256 * i;
                int p = u >> 9, rem = u & 511, n = rem >> 3, c8 = rem & 7;
                wv[i] = *(const short8*)(Wt + (size_t)p * DK * D_MODEL
                                          + (size_t)(ch * 64 + n) * D_MODEL + k0 + 64 + c8 * 8);
            }
        }
        #pragma unroll
        for (int ks = 0; ks < 2; ks++) {
            short8 a = *(const short8*)&xs[16 * rg + l15][ks * 32 + quad * 8];
            #pragma unroll
            for (int p = 0; p < 3; p++)
                #pragma unroll
                for (int n = 0; n < 2; n++) {
                    short8 bf = *(const short8*)&Ws[p][nh * 32 + n * 16 + l15][ks * 32 + quad * 8];
                    if (p < 2)
                        acc[p][n] = __builtin_amdgcn_mfma_f32_16x16x32_bf16(a, bf, acc[p][n], 0, 0, 0);
                    else
                        acc[p][n] = __builtin_amdgcn_mfma_f32_16x16x32_bf16(bf, a, acc[p][n], 0, 0, 0);
                }
        }
        __syncthreads();
    }

    #pragma unroll
    for (int n = 0; n < 2; n++)
        #pragma unroll
        for (int r = 0; r < 4; r++) {   // Q/K: row=t, col=d
            int col = ch * 64 + nh * 32 + n * 16;
            Qb[(size_t)(row0 + 16 * rg + quad * 4 + r) * DK + col + l15] = f2b(acc[0][n][r]);
            Kb[(size_t)(row0 + 16 * rg + quad * 4 + r) * DK + col + l15] = f2b(acc[1][n][r]);
            // V: row=d, col=t
            Vt[(size_t)(col + quad * 4 + r) * M_ROWS + row0 + 16 * rg + l15] = f2b(acc[2][n][r]);
        }
}

// ---------------------------------------------------------------------------
// attn_mfma (+ fused out-projection): grid 512, block 512 (8 waves).
// One q-tile (16 queries) per block; complement-pair dispatch (CU co-hosts
// qt=127-j and qt=j, 2 blocks/CU). Per 128-key iter:
//   [ds_write V(it) | QK from GLOBAL K strips | softmax | Psh] bar
//   [issue V(it+1)+K(it+1) loads; PV from Vsh+Psh] bar
// 2 barriers, 100KB LDS traffic (K never transits LDS: wave w reads only
// its own 16-key strip = contiguous 4KB in L2). No-max softmax (|s|<~3).
// O = 4 VGPR/wave (own d-strip). Psh reused as normalized-O for Wo epilogue.
// ---------------------------------------------------------------------------
__global__ __launch_bounds__(512, 4) void attn_mfma(
    const unsigned short* __restrict__ Qb, const unsigned short* __restrict__ Kb,
    const unsigned short* __restrict__ Vt, const unsigned short* __restrict__ Wot,
    float* __restrict__ out)
{
    const int bid = blockIdx.x;
    const int qt = (bid < 256) ? (127 - (bid >> 2)) : ((bid - 256) >> 2);
    const int b  = bid & 3;
    const int q0 = qt * 16;
    const int tid = threadIdx.x;
    const int w = tid >> 6;              // 0..7
    const int lane = tid & 63;
    const int l15 = lane & 15, quad = lane >> 4;

    __shared__ unsigned short Vsh[128][136];    // V chunk (34.8 KB)
    __shared__ unsigned short Psh[16][136];     // P, later normalized O (4.4 KB)
    __shared__ float Lsh[8][16];                // 0.5 KB

    const int qg = q0 + l15;
    const int nchk = (qt >> 3) + 1;      // 128-key chunks

    short8 qf[4];                        // B-operand: [n=query=l15][k=dim]
    {
        const unsigned short* qp = Qb + (size_t)(b * T_SEQ + q0 + l15) * DK + quad * 8;
        #pragma unroll
        for (int ks = 0; ks < 4; ks++) qf[ks] = *(const short8*)(qp + ks * 32);
    }

    f32x4 of = (f32x4)(0.f);             // O strip: d=w*16+l15, q=quad*4+r
    float l_part = 0.f;

    // cooperative V staging: thread covers d rows rr+32i (i<4), 16B at key col cc*8
    const int rr = tid >> 4, cc = tid & 15;
    const unsigned short* vbase = Vt + (size_t)b * T_SEQ + (size_t)cc * 8;
    // per-wave K strip base: keys w*16 + l15, dims quad*8..
    const unsigned short* kstrip = Kb + (size_t)(b * T_SEQ + w * 16 + l15) * DK + quad * 8;

    short8 vr[4], kf[4];
    #pragma unroll
    for (int i = 0; i < 4; i++)          // V chunk 0 -> regs
        vr[i] = *(const short8*)(vbase + (size_t)(rr + 32 * i) * M_ROWS);
    #pragma unroll
    for (int ks = 0; ks < 4; ks++)       // K strip chunk 0 -> regs
        kf[ks] = *(const short8*)(kstrip + ks * 32);

    for (int it = 0; it < nchk; ++it) {
        const int kc = it * 128;

        // ---- phase 1: stage V(it); QK from global K strip; softmax; Psh ----
        #pragma unroll
        for (int i = 0; i < 4; i++)
            *(short8*)&Vsh[rr + 32 * i][cc * 8] = vr[i];

        f32x4 cqk = (f32x4)(0.f);
        #pragma unroll
        for (int ks = 0; ks < 4; ks++)
            cqk = __builtin_amdgcn_mfma_f32_16x16x32_bf16(kf[ks], qf[ks], cqk, 0, 0, 0);

        // strip softmax (no-max): lane = query l15, keys kc+w*16+quad*4+r
        ushort4 pk;
        if (it == nchk - 1) {            // only the last chunk crosses the diagonal
            #pragma unroll
            for (int r = 0; r < 4; r++) {
                int key_g = kc + w * 16 + quad * 4 + r;
                float p = __expf((key_g <= qg) ? cqk[r] * SCALE : -1e30f);
                l_part += p;
                ((unsigned short*)&pk)[r] = f2b(p);
            }
        } else {
            #pragma unroll
            for (int r = 0; r < 4; r++) {
                float p = __expf(cqk[r] * SCALE);
                l_part += p;
                ((unsigned short*)&pk)[r] = f2b(p);
            }
        }
        *(ushort4*)&Psh[l15][w * 16 + quad * 4] = pk;
        __syncthreads();                 // Vsh(it) + Psh(it) ready

        // ---- phase 2: prefetch next chunk; PV ----
        if (it + 1 < nchk) {
            const int kn = kc + 128;
            #pragma unroll
            for (int i = 0; i < 4; i++)
                vr[i] = *(const short8*)(vbase + (size_t)(rr + 32 * i) * M_ROWS + kn);
            #pragma unroll
            for (int ks = 0; ks < 4; ks++)
                kf[ks] = *(const short8*)(kstrip + (size_t)kn * DK + ks * 32);
        }
        #pragma unroll
        for (int ks = 0; ks < 4; ks++) {
            short8 pf = *(const short8*)&Psh[l15][ks * 32 + quad * 8];
            short8 vf = *(const short8*)&Vsh[w * 16 + l15][ks * 32 + quad * 8];
            of = __builtin_amdgcn_mfma_f32_16x16x32_bf16(pf, vf, of, 0, 0, 0);
        }
        __syncthreads();                 // Vsh/Psh reads done -> next iter may overwrite
    }

    // per-query l: reduce quads, then waves via LDS
    float ls = l_part;
    ls += __shfl_xor(ls, 16, 64);
    ls += __shfl_xor(ls, 32, 64);
    if (quad == 0) Lsh[w][l15] = ls;
    __syncthreads();
    if (tid < 16) {
        float s = 0.f;
        #pragma unroll
        for (int w2 = 0; w2 < 8; w2++) s += Lsh[w2][tid];
        Lsh[0][tid] = 1.f / s;
    }
    __syncthreads();

    // normalize O into Psh (reused as Obs): lane holds d=w*16+l15, q=quad*4+r
    #pragma unroll
    for (int r = 0; r < 4; r++) {
        float invl = Lsh[0][quad * 4 + r];
        Psh[quad * 4 + r][w * 16 + l15] = f2b(of[r] * invl);
    }
    __syncthreads();

    // fused out-projection: wave w covers out cols w*128 .. +127.
    // Wo fragments pipelined: load sub+1 while computing sub.
    short8 af[4];
    #pragma unroll
    for (int ks = 0; ks < 4; ks++)
        af[ks] = *(const short8*)&Psh[l15][ks * 32 + quad * 8];

    const unsigned short* wbase = Wot + (size_t)(w * 128 + l15) * DK + quad * 8;
    short8 bc[4];
    #pragma unroll
    for (int ks = 0; ks < 4; ks++)
        bc[ks] = *(const short8*)(wbase + ks * 32);

    #pragma unroll
    for (int sub = 0; sub < 8; sub++) {
        short8 bn[4];
        if (sub + 1 < 8) {
            #pragma unroll
            for (int ks = 0; ks < 4; ks++)
                bn[ks] = *(const short8*)(wbase + (size_t)(sub + 1) * 16 * DK + ks * 32);
        }
        f32x4 acc2 = (f32x4)(0.f);
        #pragma unroll
        for (int ks = 0; ks < 4; ks++)
            acc2 = __builtin_amdgcn_mfma_f32_16x16x32_bf16(af[ks], bc[ks], acc2, 0, 0, 0);
        #pragma unroll
        for (int r = 0; r < 4; r++)
            out[(size_t)(b * T_SEQ + q0 + quad * 4 + r) * D_MODEL
                + w * 128 + sub * 16 + l15] = acc2[r];
        if (sub + 1 < 8) {
            #pragma unroll
            for (int ks = 0; ks < 4; ks++) bc[ks] = bn[ks];
        }
    }
}

// ---------------------------------------------------------------------------
extern "C" void kernel_launch(void* const* d_in, const int* in_sizes, int n_in,
                              void* d_out, int out_size, void* d_ws, size_t ws_size,
                              hipStream_t stream)
{
    const float* x  = (const float*)d_in[0];
    const float* Wq = (const float*)d_in[1];
    const float* Wk = (const float*)d_in[2];
    const float* Wv = (const float*)d_in[3];
    const float* Wo = (const float*)d_in[4];
    float* out = (float*)d_out;

    unsigned short* ws  = (unsigned short*)d_ws;
    unsigned short* Qb  = ws;                    // [8192][128] bf16  (2 MB)
    unsigned short* Kb  = ws + 1048576;          // [8192][128]
    unsigned short* Vt  = ws + 2097152;          // [128][8192] (V transposed)
    unsigned short* Wt  = ws + 3145728;          // [3][128][1024]
    unsigned short* Wot = ws + 3145728 + 393216; // [1024][128]

    prep_w   <<<dim3(16, 4), 256, 0, stream>>>(Wq, Wk, Wv, Wo, Wt, Wot);
    qkv_mfma <<<dim3(512),   256, 0, stream>>>(x, Wt, Qb, Kb, Vt);
    attn_mfma<<<dim3(512),   512, 0, stream>>>(Qb, Kb, Vt, Wot, out);
}

// Round 9
// 139.522 us; speedup vs baseline: 1.0300x; 1.0300x over previous
//
#include <hip/hip_runtime.h>

// B=4, T=2048, D=1024, DK=128. Inputs fp32, output fp32.
// bf16 MFMA everywhere (16x16x32), fp32 accumulate.
// Layouts (HW-verified): A[m=lane&15][k=quad*8+j], B[n=lane&15][k=quad*8+j],
// C/D[col=lane&15][row=quad*4+reg].
// R17: R8 regressed (46.4 vs R7 <42.8): per-wave K strips exposed the K load
//      latency inside the 2-barrier loop, and SQ_LDS_BANK_CONFLICT=1.32M
//      fingered the [.][136]-padded strip reads. This round: REVERT to R7's
//      cooperative time-shared K/V staging (prefetch a full phase ahead) and
//      replace padding with the T2 XOR swizzle (linear [128][128], col ^=
//      (row&7)<<3 shorts, same involution on write and read). Psh swizzled
//      too. Keeps R8's pipelined Wo epilogue. qkv/prep unchanged.
#define BATCH 4
#define T_SEQ 2048
#define D_MODEL 1024
#define DK 128
#define M_ROWS 8192
#define SCALE 0.088388347648318447f     // 1/sqrt(128)

typedef __attribute__((ext_vector_type(8))) short short8;
typedef __attribute__((ext_vector_type(4))) float f32x4;

__device__ __forceinline__ unsigned short f2b(float f) {
    unsigned int x = __float_as_uint(f);
    return (unsigned short)((x + 0x7FFFu + ((x >> 16) & 1u)) >> 16);  // RNE
}

// XOR swizzle (shorts): flips the 16B slot within each 128B half-row by row&7.
#define SWZ(r, c) ((c) ^ (((r) & 7) << 3))

// ---------------------------------------------------------------------------
// prep_w: weights fp32 -> bf16, transposed to k-contiguous. grid (16,4), 256.
//   p<3 : Wt[p][n=128][k=1024] = W_p[k][n]
//   p==3: Wot[n=1024][k=128]   = Wo[k][n]
// ---------------------------------------------------------------------------
__global__ __launch_bounds__(256) void prep_w(
    const float* __restrict__ Wq, const float* __restrict__ Wk,
    const float* __restrict__ Wv, const float* __restrict__ Wo,
    unsigned short* __restrict__ Wt, unsigned short* __restrict__ Wot)
{
    __shared__ unsigned short t[64][132];
    const int tid = threadIdx.x;
    const int p = blockIdx.y;
    if (p < 3) {
        const float* W = (p == 0) ? Wq : (p == 1) ? Wk : Wv;
        const int k0 = blockIdx.x * 64;
        #pragma unroll
        for (int i = 0; i < 8; i++) {
            int u = tid + 256 * i;              // 2048 float4 units (64k x 32)
            int r = u >> 5, c4 = u & 31;
            float4 v = *(const float4*)(W + (size_t)(k0 + r) * DK + c4 * 4);
            *(ushort4*)&t[r][c4 * 4] = make_ushort4(f2b(v.x), f2b(v.y), f2b(v.z), f2b(v.w));
        }
        __syncthreads();
        unsigned short* outp = Wt + (size_t)p * DK * D_MODEL;
        #pragma unroll
        for (int i = 0; i < 8; i++) {
            int u = tid + 256 * i;              // 128n x 16 k-quads
            int n = u >> 4, k4 = u & 15;
            ushort4 o = make_ushort4(t[k4 * 4 + 0][n], t[k4 * 4 + 1][n],
                                     t[k4 * 4 + 2][n], t[k4 * 4 + 3][n]);
            *(ushort4*)(outp + (size_t)n * D_MODEL + k0 + k4 * 4) = o;
        }
    } else {
        const int kt = blockIdx.x & 1, nt = blockIdx.x >> 1;
        const int k0 = kt * 64, n0 = nt * 128;
        #pragma unroll
        for (int i = 0; i < 8; i++) {
            int u = tid + 256 * i;
            int r = u >> 5, c4 = u & 31;
            float4 v = *(const float4*)(Wo + (size_t)(k0 + r) * D_MODEL + n0 + c4 * 4);
            *(ushort4*)&t[r][c4 * 4] = make_ushort4(f2b(v.x), f2b(v.y), f2b(v.z), f2b(v.w));
        }
        __syncthreads();
        #pragma unroll
        for (int i = 0; i < 8; i++) {
            int u = tid + 256 * i;
            int n = u >> 4, k4 = u & 15;
            ushort4 o = make_ushort4(t[k4 * 4 + 0][n], t[k4 * 4 + 1][n],
                                     t[k4 * 4 + 2][n], t[k4 * 4 + 3][n]);
            *(ushort4*)(Wot + (size_t)(n0 + n) * DK + k0 + k4 * 4) = o;
        }
    }
}

// ---------------------------------------------------------------------------
// qkv_mfma (fused Q,K,V): grid 512 (= 256 rowTiles x 2 colHalves), block 256
// (4 waves). Block: 32 rows x 64 cols of all 3 projections. (unchanged)
// ---------------------------------------------------------------------------
__global__ __launch_bounds__(256, 2) void qkv_mfma(
    const float* __restrict__ x, const unsigned short* __restrict__ Wt,
    unsigned short* __restrict__ Qb, unsigned short* __restrict__ Kb,
    unsigned short* __restrict__ Vt)
{
    const int row0 = (blockIdx.x >> 1) * 32;
    const int ch   = blockIdx.x & 1;         // col half: cols ch*64 .. +63
    const int tid = threadIdx.x;
    const int w = tid >> 6, lane = tid & 63;
    const int l15 = lane & 15, quad = lane >> 4;
    const int rg = w & 1, nh = w >> 1;

    __shared__ unsigned short xs[32][72];        // 4.6 KB
    __shared__ unsigned short Ws[3][64][72];     // 27.6 KB

    f32x4 acc[3][2];
    #pragma unroll
    for (int p = 0; p < 3; p++)
        #pragma unroll
        for (int n = 0; n < 2; n++) acc[p][n] = (f32x4)(0.f);

    float4 xv[2];
    short8 wv[6];
    #pragma unroll
    for (int i = 0; i < 2; i++) {               // preload x chunk 0 (32r x 64k fp32)
        int u = tid + 256 * i;
        int r = u >> 4, c4 = u & 15;
        xv[i] = *(const float4*)(x + (size_t)(row0 + r) * D_MODEL + c4 * 4);
    }
    #pragma unroll
    for (int i = 0; i < 6; i++) {               // preload W chunk 0 (3p x 64n x 64k)
        int u = tid + 256 * i;
        int p = u >> 9, rem = u & 511, n = rem >> 3, c8 = rem & 7;
        wv[i] = *(const short8*)(Wt + (size_t)p * DK * D_MODEL
                                  + (size_t)(ch * 64 + n) * D_MODEL + c8 * 8);
    }

    for (int k0 = 0; k0 < D_MODEL; k0 += 64) {
        #pragma unroll
        for (int i = 0; i < 2; i++) {
            int u = tid + 256 * i;
            int r = u >> 4, c4 = u & 15;
            *(ushort4*)&xs[r][c4 * 4] =
                make_ushort4(f2b(xv[i].x), f2b(xv[i].y), f2b(xv[i].z), f2b(xv[i].w));
        }
        #pragma unroll
        for (int i = 0; i < 6; i++) {
            int u = tid + 256 * i;
            int p = u >> 9, rem = u & 511, n = rem >> 3, c8 = rem & 7;
            *(short8*)&Ws[p][n][c8 * 8] = wv[i];
        }
        __syncthreads();
        if (k0 + 64 < D_MODEL) {                // issue next chunk loads under MFMA
            #pragma unroll
            for (int i = 0; i < 2; i++) {
                int u = tid + 256 * i;
                int r = u >> 4, c4 = u & 15;
                xv[i] = *(const float4*)(x + (size_t)(row0 + r) * D_MODEL + k0 + 64 + c4 * 4);
            }
            #pragma unroll
            for (int i = 0; i < 6; i++) {
                int u = tid + 256 * i;
                int p = u >> 9, rem = u & 511, n = rem >> 3, c8 = rem & 7;
                wv[i] = *(const short8*)(Wt + (size_t)p * DK * D_MODEL
                                          + (size_t)(ch * 64 + n) * D_MODEL + k0 + 64 + c8 * 8);
            }
        }
        #pragma unroll
        for (int ks = 0; ks < 2; ks++) {
            short8 a = *(const short8*)&xs[16 * rg + l15][ks * 32 + quad * 8];
            #pragma unroll
            for (int p = 0; p < 3; p++)
                #pragma unroll
                for (int n = 0; n < 2; n++) {
                    short8 bf = *(const short8*)&Ws[p][nh * 32 + n * 16 + l15][ks * 32 + quad * 8];
                    if (p < 2)
                        acc[p][n] = __builtin_amdgcn_mfma_f32_16x16x32_bf16(a, bf, acc[p][n], 0, 0, 0);
                    else
                        acc[p][n] = __builtin_amdgcn_mfma_f32_16x16x32_bf16(bf, a, acc[p][n], 0, 0, 0);
                }
        }
        __syncthreads();
    }

    #pragma unroll
    for (int n = 0; n < 2; n++)
        #pragma unroll
        for (int r = 0; r < 4; r++) {   // Q/K: row=t, col=d
            int col = ch * 64 + nh * 32 + n * 16;
            Qb[(size_t)(row0 + 16 * rg + quad * 4 + r) * DK + col + l15] = f2b(acc[0][n][r]);
            Kb[(size_t)(row0 + 16 * rg + quad * 4 + r) * DK + col + l15] = f2b(acc[1][n][r]);
            // V: row=d, col=t
            Vt[(size_t)(col + quad * 4 + r) * M_ROWS + row0 + 16 * rg + l15] = f2b(acc[2][n][r]);
        }
}

// ---------------------------------------------------------------------------
// attn_mfma (+ fused out-projection): grid 512, block 512 (8 waves).
// One q-tile (16 queries) per block; complement-pair dispatch (CU co-hosts
// qt=127-j and qt=j, 2 blocks/CU). R7 cooperative structure, XOR-swizzled:
//   [Ssh=K(it)] QK(strip w) + softmax + Psh | bar | write V(it); load K(it+1)
//   | bar | PV(d-strip w) | bar | write K(it+1); load V(it+1) | bar
// All LDS buffers linear-width-128 with col ^= (row&7)<<3 (both sides).
// No-max softmax (|s|<~3 bounded). O = 4 VGPR/wave (own d-strip).
// Psh reused as the normalized-O buffer for the pipelined Wo epilogue.
// ---------------------------------------------------------------------------
__global__ __launch_bounds__(512, 4) void attn_mfma(
    const unsigned short* __restrict__ Qb, const unsigned short* __restrict__ Kb,
    const unsigned short* __restrict__ Vt, const unsigned short* __restrict__ Wot,
    float* __restrict__ out)
{
    const int bid = blockIdx.x;
    const int qt = (bid < 256) ? (127 - (bid >> 2)) : ((bid - 256) >> 2);
    const int b  = bid & 3;
    const int q0 = qt * 16;
    const int tid = threadIdx.x;
    const int w = tid >> 6;              // 0..7
    const int lane = tid & 63;
    const int l15 = lane & 15, quad = lane >> 4;

    __shared__ unsigned short Ssh[128][128];    // K/V time-shared, swizzled (32 KB)
    __shared__ unsigned short Psh[16][128];     // P / normalized O, swizzled (4 KB)
    __shared__ float Lsh[8][16];                // 0.5 KB

    const int qg = q0 + l15;
    const int nchk = (qt >> 3) + 1;      // 128-key chunks

    short8 qf[4];                        // B-operand: [n=query=l15][k=dim]
    {
        const unsigned short* qp = Qb + (size_t)(b * T_SEQ + q0 + l15) * DK + quad * 8;
        #pragma unroll
        for (int ks = 0; ks < 4; ks++) qf[ks] = *(const short8*)(qp + ks * 32);
    }

    f32x4 of = (f32x4)(0.f);             // O strip: d=w*16+l15, q=quad*4+r
    float l_part = 0.f;

    // cooperative staging: thread covers rows rr+32i (i<4), 16B slot cc
    const int rr = tid >> 4, cc = tid & 15;
    const unsigned short* kbase = Kb + (size_t)b * T_SEQ * DK + (size_t)cc * 8;
    const unsigned short* vbase = Vt + (size_t)b * T_SEQ + (size_t)cc * 8;
    const int srow = w * 16 + l15;       // strip row this lane reads (QK and PV)

    short8 kr[4], vr[4];
    #pragma unroll
    for (int i = 0; i < 4; i++)          // K chunk 0 -> regs -> LDS (swizzled)
        kr[i] = *(const short8*)(kbase + (size_t)(rr + 32 * i) * DK);
    #pragma unroll
    for (int i = 0; i < 4; i++)
        *(short8*)&Ssh[rr + 32 * i][SWZ(rr + 32 * i, cc * 8)] = kr[i];
    #pragma unroll
    for (int i = 0; i < 4; i++)          // V chunk 0 -> regs
        vr[i] = *(const short8*)(vbase + (size_t)(rr + 32 * i) * M_ROWS);
    __syncthreads();

    for (int it = 0; it < nchk; ++it) {
        const int kc = it * 128;

        // ---- QK: wave w computes S^T for key strip w*16..+15 ----
        f32x4 cqk = (f32x4)(0.f);
        #pragma unroll
        for (int ks = 0; ks < 4; ks++) {
            short8 kf = *(const short8*)&Ssh[srow][SWZ(srow, ks * 32 + quad * 8)];
            cqk = __builtin_amdgcn_mfma_f32_16x16x32_bf16(kf, qf[ks], cqk, 0, 0, 0);
        }
        // strip softmax (no-max): lane = query l15, keys kc+w*16+quad*4+r
        ushort4 pk;
        if (it == nchk - 1) {            // only the last chunk crosses the diagonal
            #pragma unroll
            for (int r = 0; r < 4; r++) {
                int key_g = kc + w * 16 + quad * 4 + r;
                float p = __expf((key_g <= qg) ? cqk[r] * SCALE : -1e30f);
                l_part += p;
                ((unsigned short*)&pk)[r] = f2b(p);
            }
        } else {
            #pragma unroll
            for (int r = 0; r < 4; r++) {
                float p = __expf(cqk[r] * SCALE);
                l_part += p;
                ((unsigned short*)&pk)[r] = f2b(p);
            }
        }
        *(ushort4*)&Psh[l15][SWZ(l15, w * 16 + quad * 4)] = pk;
        __syncthreads();                 // K reads done; Psh ready

        // stage V(it); prefetch K(it+1) into regs
        #pragma unroll
        for (int i = 0; i < 4; i++)
            *(short8*)&Ssh[rr + 32 * i][SWZ(rr + 32 * i, cc * 8)] = vr[i];
        if (it + 1 < nchk) {
            #pragma unroll
            for (int i = 0; i < 4; i++)
                kr[i] = *(const short8*)(kbase + (size_t)(kc + 128 + rr + 32 * i) * DK);
        }
        __syncthreads();                 // Vsh ready

        // ---- PV: wave w accumulates d strip w*16..+15 ----
        #pragma unroll
        for (int ks = 0; ks < 4; ks++) {
            short8 pf = *(const short8*)&Psh[l15][SWZ(l15, ks * 32 + quad * 8)];
            short8 vf = *(const short8*)&Ssh[srow][SWZ(srow, ks * 32 + quad * 8)];
            of = __builtin_amdgcn_mfma_f32_16x16x32_bf16(pf, vf, of, 0, 0, 0);
        }
        __syncthreads();                 // V reads done

        if (it + 1 < nchk) {             // stage K(it+1); prefetch V(it+1)
            #pragma unroll
            for (int i = 0; i < 4; i++)
                *(short8*)&Ssh[rr + 32 * i][SWZ(rr + 32 * i, cc * 8)] = kr[i];
            #pragma unroll
            for (int i = 0; i < 4; i++)
                vr[i] = *(const short8*)(vbase + (size_t)(rr + 32 * i) * M_ROWS + kc + 128);
        }
        __syncthreads();                 // Ksh ready for next iter
    }

    // per-query l: reduce quads, then waves via LDS
    float ls = l_part;
    ls += __shfl_xor(ls, 16, 64);
    ls += __shfl_xor(ls, 32, 64);
    if (quad == 0) Lsh[w][l15] = ls;
    __syncthreads();
    if (tid < 16) {
        float s = 0.f;
        #pragma unroll
        for (int w2 = 0; w2 < 8; w2++) s += Lsh[w2][tid];
        Lsh[0][tid] = 1.f / s;
    }
    __syncthreads();

    // normalize O into Psh (reused as Obs): lane holds d=w*16+l15, q=quad*4+r
    #pragma unroll
    for (int r = 0; r < 4; r++) {
        float invl = Lsh[0][quad * 4 + r];
        Psh[quad * 4 + r][SWZ(quad * 4 + r, w * 16 + l15)] = f2b(of[r] * invl);
    }
    __syncthreads();

    // fused out-projection: wave w covers out cols w*128 .. +127.
    // Wo fragments pipelined: load sub+1 while computing sub.
    short8 af[4];
    #pragma unroll
    for (int ks = 0; ks < 4; ks++)
        af[ks] = *(const short8*)&Psh[l15][SWZ(l15, ks * 32 + quad * 8)];

    const unsigned short* wbase = Wot + (size_t)(w * 128 + l15) * DK + quad * 8;
    short8 bc[4];
    #pragma unroll
    for (int ks = 0; ks < 4; ks++)
        bc[ks] = *(const short8*)(wbase + ks * 32);

    #pragma unroll
    for (int sub = 0; sub < 8; sub++) {
        short8 bn[4];
        if (sub + 1 < 8) {
            #pragma unroll
            for (int ks = 0; ks < 4; ks++)
                bn[ks] = *(const short8*)(wbase + (size_t)(sub + 1) * 16 * DK + ks * 32);
        }
        f32x4 acc2 = (f32x4)(0.f);
        #pragma unroll
        for (int ks = 0; ks < 4; ks++)
            acc2 = __builtin_amdgcn_mfma_f32_16x16x32_bf16(af[ks], bc[ks], acc2, 0, 0, 0);
        #pragma unroll
        for (int r = 0; r < 4; r++)
            out[(size_t)(b * T_SEQ + q0 + quad * 4 + r) * D_MODEL
                + w * 128 + sub * 16 + l15] = acc2[r];
        if (sub + 1 < 8) {
            #pragma unroll
            for (int ks = 0; ks < 4; ks++) bc[ks] = bn[ks];
        }
    }
}

// ---------------------------------------------------------------------------
extern "C" void kernel_launch(void* const* d_in, const int* in_sizes, int n_in,
                              void* d_out, int out_size, void* d_ws, size_t ws_size,
                              hipStream_t stream)
{
    const float* x  = (const float*)d_in[0];
    const float* Wq = (const float*)d_in[1];
    const float* Wk = (const float*)d_in[2];
    const float* Wv = (const float*)d_in[3];
    const float* Wo = (const float*)d_in[4];
    float* out = (float*)d_out;

    unsigned short* ws  = (unsigned short*)d_ws;
    unsigned short* Qb  = ws;                    // [8192][128] bf16  (2 MB)
    unsigned short* Kb  = ws + 1048576;          // [8192][128]
    unsigned short* Vt  = ws + 2097152;          // [128][8192] (V transposed)
    unsigned short* Wt  = ws + 3145728;          // [3][128][1024]
    unsigned short* Wot = ws + 3145728 + 393216; // [1024][128]

    prep_w   <<<dim3(16, 4), 256, 0, stream>>>(Wq, Wk, Wv, Wo, Wt, Wot);
    qkv_mfma <<<dim3(512),   256, 0, stream>>>(x, Wt, Qb, Kb, Vt);
    attn_mfma<<<dim3(512),   512, 0, stream>>>(Qb, Kb, Vt, Wot, out);
}